// Round 4
// baseline (2084.596 us; speedup 1.0000x reference)
//
#include <hip/hip_runtime.h>
#include <stdint.h>

// Problem constants: V=32000, B=64, T=256, D=512, H=1024
typedef unsigned short u16;
typedef unsigned int u32;
typedef __attribute__((ext_vector_type(4))) unsigned int u32x4;
typedef __attribute__((ext_vector_type(4))) float f32x4;
typedef __attribute__((ext_vector_type(8))) __bf16 bf16x8;

#define MFMA16(a, b, c) __builtin_amdgcn_mfma_f32_16x16x32_bf16((a), (b), (c), 0, 0, 0)

__device__ __forceinline__ u16 f2b(float f) {
  union { float f; unsigned u; } v; v.f = f;
  unsigned r = v.u + 0x7FFFu + ((v.u >> 16) & 1u);
  return (u16)(r >> 16);
}
__device__ __forceinline__ float b2f(u16 h) {
  union { unsigned u; float f; } v; v.u = ((unsigned)h) << 16;
  return v.f;
}
__device__ __forceinline__ float sigm(float x) { return 1.0f / (1.0f + __expf(-x)); }
__device__ __forceinline__ float tanh_fast(float x) {
  x = fminf(fmaxf(x, -15.0f), 15.0f);
  float t = __expf(2.0f * x);
  return (t - 1.0f) / (t + 1.0f);
}

// ---- LLC-coherent (write-through / cache-bypass) access helpers ----
template <int OFF>
__device__ __forceinline__ u32x4 ld16_sc(const u16* p) {
  u32x4 r;
  asm volatile("global_load_dwordx4 %0, %1, off offset:%2 sc0 sc1"
               : "=v"(r) : "v"(p), "i"(OFF));
  return r;
}
__device__ __forceinline__ void st16_sc(u16* p, u32x4 v) {
  asm volatile("global_store_dwordx4 %0, %1, off sc0 sc1"
               :: "v"(p), "v"(v) : "memory");
}
__device__ __forceinline__ void st4_sc(u32* p, u32 v) {
  asm volatile("global_store_dword %0, %1, off sc0 sc1"
               :: "v"(p), "v"(v) : "memory");
}
__device__ __forceinline__ u32 ld4_sc(const u32* p) {
  u32 r;
  asm volatile("global_load_dword %0, %1, off sc0 sc1\n\t"
               "s_waitcnt vmcnt(0)"
               : "=v"(r) : "v"(p) : "memory");
  return r;
}

// ---------------- prep kernels ----------------

// src[R][C] f32 -> dst[C][R] bf16 (B^T layout for GEMM / scan)
__global__ void transpose_cvt(const float* __restrict__ src, u16* __restrict__ dst,
                              int R, int C) {
  __shared__ float tile[32][33];
  const int c0 = blockIdx.x * 32, r0 = blockIdx.y * 32;
  const int tx = threadIdx.x, ty = threadIdx.y;
  for (int i = ty; i < 32; i += 8)
    tile[i][tx] = src[(size_t)(r0 + i) * C + (c0 + tx)];
  __syncthreads();
  for (int i = ty; i < 32; i += 8)
    dst[(size_t)(c0 + i) * R + (r0 + tx)] = f2b(tile[tx][i]);
}

// A_emb[m][0:512] = bf16(emb_table[y[m]][:]) ; m = b*T + t (y flat order)
__global__ void gather_cast(const int* __restrict__ y, const float* __restrict__ tab,
                            u16* __restrict__ A) {
  const int idx = blockIdx.x * 256 + threadIdx.x;
  const int m = idx >> 7;
  const int d0 = (idx & 127) << 2;
  const float4 v = *reinterpret_cast<const float4*>(tab + (size_t)y[m] * 512 + d0);
  ushort4 o;
  o.x = f2b(v.x); o.y = f2b(v.y); o.z = f2b(v.z); o.w = f2b(v.w);
  *reinterpret_cast<ushort4*>(A + (size_t)m * 512 + d0) = o;
}

__global__ void cast_h0(const float* __restrict__ h, u16* __restrict__ dst, int n) {
  const int i = blockIdx.x * 256 + threadIdx.x;
  if (i < n) dst[i] = f2b(h[i]);
}

// ---------------- GEMM: C[m][n] = A[m][K] * Bt[n][K]^T + bias ----------------
template <int EPI>
__global__ __launch_bounds__(256, 2) void gemm_bt(
    const u16* __restrict__ A, const u16* __restrict__ Bt,
    const float* __restrict__ bias, void* __restrict__ Cout,
    int M, int N, int K) {
  __shared__ u16 As[4096], Bs[4096];
  const int tid = threadIdx.x, lane = tid & 63, w = tid >> 6;
  const int wm = w >> 1, wn = w & 1, c = lane & 15, hq = lane >> 4;
  const int m0 = blockIdx.y * 128, n0 = blockIdx.x * 128;
  f32x4 acc[4][4] = {};

  const int slot0 = tid, slot1 = 256 + tid;
  const int r0_ = slot0 >> 2, ko0 = (slot0 & 3) << 3;
  const int r1_ = slot1 >> 2, ko1 = (slot1 & 3) << 3;

  for (int k0 = 0; k0 < K; k0 += 32) {
    const u32x4 a0 = *(const u32x4*)(A + (size_t)(m0 + r0_) * K + k0 + ko0);
    const u32x4 a1 = *(const u32x4*)(A + (size_t)(m0 + r1_) * K + k0 + ko1);
    const u32x4 b0 = *(const u32x4*)(Bt + (size_t)(n0 + r0_) * K + k0 + ko0);
    const u32x4 b1 = *(const u32x4*)(Bt + (size_t)(n0 + r1_) * K + k0 + ko1);
    __syncthreads();
    *(u32x4*)(As + r0_ * 32 + ko0) = a0;
    *(u32x4*)(As + r1_ * 32 + ko1) = a1;
    *(u32x4*)(Bs + r0_ * 32 + ko0) = b0;
    *(u32x4*)(Bs + r1_ * 32 + ko1) = b1;
    __syncthreads();
    u32x4 af[4], bf[4];
#pragma unroll
    for (int i = 0; i < 4; ++i) {
      af[i] = *(const u32x4*)(As + (wm * 64 + i * 16 + c) * 32 + hq * 8);
      bf[i] = *(const u32x4*)(Bs + (wn * 64 + i * 16 + c) * 32 + hq * 8);
    }
#pragma unroll
    for (int mi = 0; mi < 4; ++mi)
#pragma unroll
      for (int ni = 0; ni < 4; ++ni)
        acc[mi][ni] = MFMA16(__builtin_bit_cast(bf16x8, af[mi]),
                             __builtin_bit_cast(bf16x8, bf[ni]), acc[mi][ni]);
  }

#pragma unroll
  for (int ni = 0; ni < 4; ++ni) {
    const int col = n0 + wn * 64 + ni * 16 + c;
    const float bv = bias[col];
#pragma unroll
    for (int mi = 0; mi < 4; ++mi) {
#pragma unroll
      for (int i = 0; i < 4; ++i) {
        const int m = m0 + wm * 64 + mi * 16 + hq * 4 + i;
        const float v = acc[mi][ni][i] + bv;
        if (EPI == 0) {
          const int dr = (m & 255) * 64 + (m >> 8);       // -> [t*64+b][3072]
          ((u16*)Cout)[(size_t)dr * N + col] = f2b(v);
        } else {
          const int dr = (m & 63) * 256 + (m >> 6);       // -> [b*256+t][512]
          ((float*)Cout)[(size_t)dr * N + col] = tanh_fast(v);
        }
      }
    }
  }
}

// ---------------- persistent GRU scan (256 WGs x 5 waves) -------------------
// WG = (g, r): g = col-group (16 h-cols), r = row-group (16 rows).
// Waves s=0..3: k-split compute (K/4=256 each); wave s=4: combine + epilogue.
// Per step: [s0 polls tags] SYNCB [s0..3: af load, MFMA, red export] SYNCA
// [s4: combine, gates, LDS-transpose, coalesced h store, drain, tag publish].
__global__ __launch_bounds__(320, 1) void scan_kernel(
    const u16* __restrict__ wh_t,   // [3072][1024] bf16 (Wh^T)
    const float* __restrict__ bh,   // [3072]
    const float* __restrict__ h0,   // [64][1024] f32
    const u16* __restrict__ gx,     // [256*64][3072] bf16, t-major, incl. bx
    u16* __restrict__ hbuf2,        // [2][64][1024] bf16 exchange
    u16* __restrict__ outs,         // [256*64][1024] bf16, t-major (GEMM A)
    u32* __restrict__ tags) {       // [2][4][64]
  __shared__ u16 whs[96 * 512];       // 96 KB Wh slice, fragment-ordered
  __shared__ float red[2][4][3][256]; // 24 KB k-partial exchange, parity dbuf
  __shared__ __align__(16) u16 htile[16][16]; // epilogue transpose staging
  const int g = blockIdx.x >> 2, r = blockIdx.x & 3;
  const int tid = threadIdx.x, lane = tid & 63, s = tid >> 6;  // s in 0..4
  const int c = lane & 15, hq = lane >> 4;
  const int gcol = g * 16 + c;
  const int row0 = r * 16;

  // stage Wh slice: fb = (ss*8+kk)*3+ct, lane-linear 16B per fragment
  for (int fb = s; fb < 96; fb += 5) {
    const int ss = fb / 24, kk = (fb % 24) / 3, ct = fb % 3;
    const int n = ct * 1024 + g * 16 + c;
    const int k = ss * 256 + kk * 32 + hq * 8;
    *(u32x4*)(whs + fb * 512 + lane * 8) =
        *(const u32x4*)(wh_t + (size_t)n * 1024 + k);
  }
  float bhv[3], hprev[4];
  u16 gxr[4][3];
  if (s == 4) {
#pragma unroll
    for (int ct = 0; ct < 3; ++ct) bhv[ct] = bh[ct * 1024 + gcol];
#pragma unroll
    for (int i = 0; i < 4; ++i)
      hprev[i] = h0[(size_t)(row0 + hq * 4 + i) * 1024 + gcol];
    const u16* gp = gx + gcol;
#pragma unroll
    for (int i = 0; i < 4; ++i) {
      const int b = row0 + hq * 4 + i;
      gxr[i][0] = gp[(size_t)b * 3072];
      gxr[i][1] = gp[(size_t)b * 3072 + 1024];
      gxr[i][2] = gp[(size_t)b * 3072 + 2048];
    }
  }
  __syncthreads();

  for (int t = 0; t < 256; ++t) {
    // ---- single poll wave: all 64 producers of this row class ----
    if (s == 0 && t > 0) {
      const u32* tp = tags + (t & 1) * 256 + r * 64 + lane;
      while (true) {
        const u32 v = ld4_sc(tp);
        if (!__ballot(v < (u32)t)) break;
        __builtin_amdgcn_s_sleep(1);
      }
    }
    __syncthreads();  // SYNC B: h_t visible to every wave

    if (s < 4) {
      // batched h-fragment loads (LLC bypass), one latency for all 8
      u32x4 af[8];
      const u16* ap = hbuf2 + (size_t)(t & 1) * 65536 +
                      (size_t)(row0 + c) * 1024 + s * 256 + hq * 8;
      af[0] = ld16_sc<0 * 64>(ap);  af[1] = ld16_sc<1 * 64>(ap);
      af[2] = ld16_sc<2 * 64>(ap);  af[3] = ld16_sc<3 * 64>(ap);
      af[4] = ld16_sc<4 * 64>(ap);  af[5] = ld16_sc<5 * 64>(ap);
      af[6] = ld16_sc<6 * 64>(ap);  af[7] = ld16_sc<7 * 64>(ap);
      asm volatile("s_waitcnt vmcnt(0)" ::: "memory");
      __builtin_amdgcn_sched_barrier(0);

      f32x4 acc[3] = {};
#pragma unroll
      for (int kk = 0; kk < 8; ++kk) {
        const int fb = (s * 8 + kk) * 3;
        const u32x4 b0 = *(const u32x4*)(whs + (fb + 0) * 512 + lane * 8);
        const u32x4 b1 = *(const u32x4*)(whs + (fb + 1) * 512 + lane * 8);
        const u32x4 b2 = *(const u32x4*)(whs + (fb + 2) * 512 + lane * 8);
        const bf16x8 a = __builtin_bit_cast(bf16x8, af[kk]);
        acc[0] = MFMA16(a, __builtin_bit_cast(bf16x8, b0), acc[0]);
        acc[1] = MFMA16(a, __builtin_bit_cast(bf16x8, b1), acc[1]);
        acc[2] = MFMA16(a, __builtin_bit_cast(bf16x8, b2), acc[2]);
      }
#pragma unroll
      for (int ct = 0; ct < 3; ++ct)
        *(f32x4*)&red[t & 1][s][ct][lane * 4] = acc[ct];
    }
    __syncthreads();  // SYNC A: red[t] complete

    if (s == 4) {
      f32x4 a0 = {}, a1 = {}, a2 = {};
#pragma unroll
      for (int j = 0; j < 4; ++j) {
        a0 += *(const f32x4*)&red[t & 1][j][0][lane * 4];
        a1 += *(const f32x4*)&red[t & 1][j][1][lane * 4];
        a2 += *(const f32x4*)&red[t & 1][j][2][lane * 4];
      }
#pragma unroll
      for (int i = 0; i < 4; ++i) {
        const float xr = b2f(gxr[i][0]);
        const float xz = b2f(gxr[i][1]);
        const float xn = b2f(gxr[i][2]);
        const float rr = sigm(xr + a0[i] + bhv[0]);
        const float zz = sigm(xz + a1[i] + bhv[1]);
        const float nn = tanh_fast(xn + rr * (a2[i] + bhv[2]));
        const float hnew = (1.0f - zz) * nn + zz * hprev[i];
        hprev[i] = hnew;
        htile[hq * 4 + i][c] = f2b(hnew);   // LDS transpose staging
      }
      asm volatile("s_waitcnt lgkmcnt(0)" ::: "memory");
      __builtin_amdgcn_sched_barrier(0);
      u32x4 hv;
      int rowg = 0;
      if (lane < 32) {
        const int rr_ = lane >> 1, c8 = (lane & 1) * 8;
        rowg = row0 + rr_;
        hv = *(const u32x4*)(&htile[rr_][c8]);
        st16_sc(hbuf2 + (size_t)((t + 1) & 1) * 65536 + (size_t)rowg * 1024 +
                    g * 16 + c8, hv);
      }
      asm volatile("s_waitcnt vmcnt(0)" ::: "memory");  // h at LLC
      if (lane == 0)
        st4_sc(tags + ((t + 1) & 1) * 256 + r * 64 + g, (u32)(t + 1));
      // off-critical-path: outs copy + next gx prefetch
      if (lane < 32) {
        const int c8 = (lane & 1) * 8;
        *(u32x4*)(outs + ((size_t)t * 64 + rowg) * 1024 + g * 16 + c8) = hv;
      }
      if (t < 255) {
        const u16* gp = gx + (size_t)(t + 1) * 64 * 3072 + gcol;
#pragma unroll
        for (int i = 0; i < 4; ++i) {
          const int b = row0 + hq * 4 + i;
          gxr[i][0] = gp[(size_t)b * 3072];
          gxr[i][1] = gp[(size_t)b * 3072 + 1024];
          gxr[i][2] = gp[(size_t)b * 3072 + 2048];
        }
      }
    }
  }
}

// ---------------- host ----------------
extern "C" void kernel_launch(void* const* d_in, const int* in_sizes, int n_in,
                              void* d_out, int out_size, void* d_ws, size_t ws_size,
                              hipStream_t stream) {
  (void)in_sizes; (void)n_in; (void)out_size; (void)ws_size;
  const int* y = (const int*)d_in[0];
  const float* hidden = (const float*)d_in[1];
  const float* emb = (const float*)d_in[2];
  const float* Wx = (const float*)d_in[3];
  const float* Wh = (const float*)d_in[4];
  const float* bx = (const float*)d_in[5];
  const float* bh = (const float*)d_in[6];
  const float* Wout = (const float*)d_in[7];
  const float* bout = (const float*)d_in[8];

  char* p = (char*)d_ws;
  u16* wx_t  = (u16*)p; p += (size_t)3072 * 512 * 2;     // Wx^T  [3072][512]
  u16* wh_t  = (u16*)p; p += (size_t)3072 * 1024 * 2;    // Wh^T  [3072][1024]
  u16* wo_t  = (u16*)p; p += (size_t)512 * 1024 * 2;     // Wout^T[512][1024]
  u16* aemb  = (u16*)p; p += (size_t)16384 * 512 * 2;    // gathered emb bf16
  u16* gx    = (u16*)p; p += (size_t)16384 * 3072 * 2;   // t-major gx
  u16* outs  = (u16*)p; p += (size_t)16384 * 1024 * 2;   // h_1..h_256, t-major
  u16* hbuf2 = (u16*)p; p += (size_t)2 * 64 * 1024 * 2;  // exchange dbuf
  u32* tags  = (u32*)p;                                   // [2][4][64]

  hipMemsetAsync(tags, 0, 2 * 4 * 64 * sizeof(u32), stream);
  transpose_cvt<<<dim3(96, 16), dim3(32, 8), 0, stream>>>(Wx, wx_t, 512, 3072);
  transpose_cvt<<<dim3(96, 32), dim3(32, 8), 0, stream>>>(Wh, wh_t, 1024, 3072);
  transpose_cvt<<<dim3(16, 32), dim3(32, 8), 0, stream>>>(Wout, wo_t, 1024, 512);
  gather_cast<<<dim3(8192), dim3(256), 0, stream>>>(y, emb, aemb);
  cast_h0<<<dim3(256), dim3(256), 0, stream>>>(hidden, hbuf2, 64 * 1024);

  // gx = emb @ Wx + bx   (M=16384, N=3072, K=512)
  gemm_bt<0><<<dim3(24, 128), dim3(256), 0, stream>>>(aemb, wx_t, bx, (void*)gx,
                                                      16384, 3072, 512);
  // GRU scan (persistent 256 WGs x 5 waves, seq-tagged dataflow through LLC)
  scan_kernel<<<dim3(256), dim3(320), 0, stream>>>(wh_t, bh, hidden, gx,
                                                   hbuf2, outs, tags);
  // logits = tanh(h_1..h_256 @ Wout + bout)  (M=16384, N=512, K=1024)
  gemm_bt<1><<<dim3(4, 128), dim3(256), 0, stream>>>(outs, wo_t, bout,
                                                     d_out, 16384, 512, 1024);
}

// Round 5
// 925.920 us; speedup vs baseline: 2.2514x; 2.2514x over previous
//
#include <hip/hip_runtime.h>
#include <stdint.h>

// Problem constants: V=32000, B=64, T=256, D=512, H=1024
typedef unsigned short u16;
typedef unsigned int u32;
typedef __attribute__((ext_vector_type(4))) unsigned int u32x4;
typedef __attribute__((ext_vector_type(4))) float f32x4;
typedef __attribute__((ext_vector_type(8))) __bf16 bf16x8;

#define MFMA16(a, b, c) __builtin_amdgcn_mfma_f32_16x16x32_bf16((a), (b), (c), 0, 0, 0)

__device__ __forceinline__ u16 f2b(float f) {
  union { float f; unsigned u; } v; v.f = f;
  unsigned r = v.u + 0x7FFFu + ((v.u >> 16) & 1u);
  return (u16)(r >> 16);
}
__device__ __forceinline__ float b2f(u16 h) {
  union { unsigned u; float f; } v; v.u = ((unsigned)h) << 16;
  return v.f;
}
__device__ __forceinline__ float sigm(float x) { return 1.0f / (1.0f + __expf(-x)); }
__device__ __forceinline__ float tanh_fast(float x) {
  x = fminf(fmaxf(x, -15.0f), 15.0f);
  float t = __expf(2.0f * x);
  return (t - 1.0f) / (t + 1.0f);
}

// ---- LLC-coherent (write-through / cache-bypass) access helpers ----
template <int OFF>
__device__ __forceinline__ u32x4 ld16_sc(const u16* p) {
  u32x4 r;
  asm volatile("global_load_dwordx4 %0, %1, off offset:%2 sc0 sc1"
               : "=v"(r) : "v"(p), "i"(OFF));
  return r;
}
__device__ __forceinline__ void st16_sc(u16* p, u32x4 v) {
  asm volatile("global_store_dwordx4 %0, %1, off sc0 sc1"
               :: "v"(p), "v"(v) : "memory");
}
__device__ __forceinline__ void st4_sc(u32* p, u32 v) {
  asm volatile("global_store_dword %0, %1, off sc0 sc1"
               :: "v"(p), "v"(v) : "memory");
}
__device__ __forceinline__ u32 ld4_sc(const u32* p) {
  u32 r;
  asm volatile("global_load_dword %0, %1, off sc0 sc1\n\t"
               "s_waitcnt vmcnt(0)"
               : "=v"(r) : "v"(p) : "memory");
  return r;
}

// ---------------- prep kernels ----------------

// src[R][C] f32 -> dst[C][R] bf16 (B^T layout for GEMM / scan)
__global__ void transpose_cvt(const float* __restrict__ src, u16* __restrict__ dst,
                              int R, int C) {
  __shared__ float tile[32][33];
  const int c0 = blockIdx.x * 32, r0 = blockIdx.y * 32;
  const int tx = threadIdx.x, ty = threadIdx.y;
  for (int i = ty; i < 32; i += 8)
    tile[i][tx] = src[(size_t)(r0 + i) * C + (c0 + tx)];
  __syncthreads();
  for (int i = ty; i < 32; i += 8)
    dst[(size_t)(c0 + i) * R + (r0 + tx)] = f2b(tile[tx][i]);
}

// A_emb[m][0:512] = bf16(emb_table[y[m]][:]) ; m = b*T + t (y flat order)
__global__ void gather_cast(const int* __restrict__ y, const float* __restrict__ tab,
                            u16* __restrict__ A) {
  const int idx = blockIdx.x * 256 + threadIdx.x;
  const int m = idx >> 7;
  const int d0 = (idx & 127) << 2;
  const float4 v = *reinterpret_cast<const float4*>(tab + (size_t)y[m] * 512 + d0);
  ushort4 o;
  o.x = f2b(v.x); o.y = f2b(v.y); o.z = f2b(v.z); o.w = f2b(v.w);
  *reinterpret_cast<ushort4*>(A + (size_t)m * 512 + d0) = o;
}

// hidden[64][1024] f32 -> blocked bf16 exchange layout, parity 0:
// dst[((r*64)+g)*256 + ii*16 + j],  b = r*16+ii, n = g*16+j
__global__ void cast_h0_blocked(const float* __restrict__ h, u16* __restrict__ dst) {
  const int i = blockIdx.x * 256 + threadIdx.x;   // 65536 threads
  const int b = i >> 10, n = i & 1023;
  const int r = b >> 4, ii = b & 15, g = n >> 4, j = n & 15;
  dst[((size_t)r * 64 + g) * 256 + ii * 16 + j] = f2b(h[(size_t)b * 1024 + n]);
}

// ---------------- GEMM: C[m][n] = A[m][K] * Bt[n][K]^T + bias ----------------
template <int EPI>
__global__ __launch_bounds__(256, 2) void gemm_bt(
    const u16* __restrict__ A, const u16* __restrict__ Bt,
    const float* __restrict__ bias, void* __restrict__ Cout,
    int M, int N, int K) {
  __shared__ u16 As[4096], Bs[4096];
  const int tid = threadIdx.x, lane = tid & 63, w = tid >> 6;
  const int wm = w >> 1, wn = w & 1, c = lane & 15, hq = lane >> 4;
  const int m0 = blockIdx.y * 128, n0 = blockIdx.x * 128;
  f32x4 acc[4][4] = {};

  const int slot0 = tid, slot1 = 256 + tid;
  const int r0_ = slot0 >> 2, ko0 = (slot0 & 3) << 3;
  const int r1_ = slot1 >> 2, ko1 = (slot1 & 3) << 3;

  for (int k0 = 0; k0 < K; k0 += 32) {
    const u32x4 a0 = *(const u32x4*)(A + (size_t)(m0 + r0_) * K + k0 + ko0);
    const u32x4 a1 = *(const u32x4*)(A + (size_t)(m0 + r1_) * K + k0 + ko1);
    const u32x4 b0 = *(const u32x4*)(Bt + (size_t)(n0 + r0_) * K + k0 + ko0);
    const u32x4 b1 = *(const u32x4*)(Bt + (size_t)(n0 + r1_) * K + k0 + ko1);
    __syncthreads();
    *(u32x4*)(As + r0_ * 32 + ko0) = a0;
    *(u32x4*)(As + r1_ * 32 + ko1) = a1;
    *(u32x4*)(Bs + r0_ * 32 + ko0) = b0;
    *(u32x4*)(Bs + r1_ * 32 + ko1) = b1;
    __syncthreads();
    u32x4 af[4], bf[4];
#pragma unroll
    for (int i = 0; i < 4; ++i) {
      af[i] = *(const u32x4*)(As + (wm * 64 + i * 16 + c) * 32 + hq * 8);
      bf[i] = *(const u32x4*)(Bs + (wn * 64 + i * 16 + c) * 32 + hq * 8);
    }
#pragma unroll
    for (int mi = 0; mi < 4; ++mi)
#pragma unroll
      for (int ni = 0; ni < 4; ++ni)
        acc[mi][ni] = MFMA16(__builtin_bit_cast(bf16x8, af[mi]),
                             __builtin_bit_cast(bf16x8, bf[ni]), acc[mi][ni]);
  }

#pragma unroll
  for (int ni = 0; ni < 4; ++ni) {
    const int col = n0 + wn * 64 + ni * 16 + c;
    const float bv = bias[col];
#pragma unroll
    for (int mi = 0; mi < 4; ++mi) {
#pragma unroll
      for (int i = 0; i < 4; ++i) {
        const int m = m0 + wm * 64 + mi * 16 + hq * 4 + i;
        const float v = acc[mi][ni][i] + bv;
        if (EPI == 0) {
          const int dr = (m & 255) * 64 + (m >> 8);       // -> [t*64+b][3072]
          ((u16*)Cout)[(size_t)dr * N + col] = f2b(v);
        } else {
          const int dr = (m & 63) * 256 + (m >> 6);       // -> [b*256+t][512]
          ((float*)Cout)[(size_t)dr * N + col] = tanh_fast(v);
        }
      }
    }
  }
}

// ---------------- persistent GRU scan (256 WGs x 4 waves, R3 protocol) ------
// WG = (g, r): g = col-group (16 h-cols), r = row-group (16 rows).
// Waves s=0..3: k-split compute (256 K each); s0 additionally combines,
// runs the gate epilogue, stores the 16x16 h tile (one 512B burst) and
// publishes its tag. h exchange layout is BLOCKED: [parity][r][g][16x16].
// Tags padded to 128B/line; poll uses lanes 0..15, one unique tag each.
__global__ __launch_bounds__(256, 1) void scan_kernel(
    const u16* __restrict__ wh_t,   // [3072][1024] bf16 (Wh^T)
    const float* __restrict__ bh,   // [3072]
    const float* __restrict__ h0,   // [64][1024] f32
    const u16* __restrict__ gx,     // [256*64][3072] bf16, t-major, incl. bx
    u16* __restrict__ hbuf,         // [2][4][64][256] bf16 blocked exchange
    u16* __restrict__ outs,         // [256*64][1024] bf16, t-major (GEMM A)
    u32* __restrict__ tags) {       // [2][4][64][32] (128B-padded)
  __shared__ u16 whs[96 * 512];       // 96 KB Wh slice, fragment-ordered
  __shared__ float red[2][3][3][256]; // 18 KB k-partial exchange, parity dbuf
  __shared__ __align__(16) u16 htile[16][16]; // 512B: blocked h tile staging
  const int g = blockIdx.x >> 2, r = blockIdx.x & 3;
  const int tid = threadIdx.x, lane = tid & 63, s = tid >> 6;
  const int c = lane & 15, hq = lane >> 4;
  const int gcol = g * 16 + c;
  const int row0 = r * 16;

  // stage Wh slice, fragment-ordered: fb=(ss*8+kk)*3+ct, lane-linear 16B
  for (int fb = s; fb < 96; fb += 4) {
    const int ss = fb / 24, kk = (fb % 24) / 3, ct = fb % 3;
    const int n = ct * 1024 + g * 16 + c;
    const int k = ss * 256 + kk * 32 + hq * 8;
    *(u32x4*)(whs + fb * 512 + lane * 8) =
        *(const u32x4*)(wh_t + (size_t)n * 1024 + k);
  }
  float bhv[3], hprev[4];
  u16 gxr[4][3];
  if (s == 0) {
#pragma unroll
    for (int ct = 0; ct < 3; ++ct) bhv[ct] = bh[ct * 1024 + gcol];
#pragma unroll
    for (int i = 0; i < 4; ++i)
      hprev[i] = h0[(size_t)(row0 + hq * 4 + i) * 1024 + gcol];
    const u16* gp = gx + gcol;
#pragma unroll
    for (int i = 0; i < 4; ++i) {
      const int b = row0 + hq * 4 + i;
      gxr[i][0] = gp[(size_t)b * 3072];
      gxr[i][1] = gp[(size_t)b * 3072 + 1024];
      gxr[i][2] = gp[(size_t)b * 3072 + 2048];
    }
  }
  __syncthreads();

  for (int t = 0; t < 256; ++t) {
    // ---- poll the 16 producers of this wave's K-slice (lanes 0..15 only) ---
    if (t > 0 && lane < 16) {
      const u32* tp = tags + (((size_t)(t & 1) * 4 + r) * 64 + s * 16 + lane) * 32;
      while (__ballot(ld4_sc(tp) < (u32)t)) {}
    }

    // ---- batched h-fragment loads from blocked layout (8 KB contiguous) ----
    u32x4 af[8];
    {
      const u16* ap0 = hbuf + (((size_t)(t & 1) * 4 + r) * 64 + s * 16 + (hq >> 1)) * 256 +
                       c * 16 + (hq & 1) * 8;
      const u16* ap1 = ap0 + 2048;  // +4 blocks
      af[0] = ld16_sc<0>(ap0);    af[1] = ld16_sc<1024>(ap0);
      af[2] = ld16_sc<2048>(ap0); af[3] = ld16_sc<3072>(ap0);
      af[4] = ld16_sc<0>(ap1);    af[5] = ld16_sc<1024>(ap1);
      af[6] = ld16_sc<2048>(ap1); af[7] = ld16_sc<3072>(ap1);
    }
    asm volatile("s_waitcnt vmcnt(0)" ::: "memory");
    __builtin_amdgcn_sched_barrier(0);

    f32x4 acc[3] = {};
#pragma unroll
    for (int kk = 0; kk < 8; ++kk) {
      const int fb = (s * 8 + kk) * 3;
      const u32x4 b0 = *(const u32x4*)(whs + (fb + 0) * 512 + lane * 8);
      const u32x4 b1 = *(const u32x4*)(whs + (fb + 1) * 512 + lane * 8);
      const u32x4 b2 = *(const u32x4*)(whs + (fb + 2) * 512 + lane * 8);
      const bf16x8 a = __builtin_bit_cast(bf16x8, af[kk]);
      acc[0] = MFMA16(a, __builtin_bit_cast(bf16x8, b0), acc[0]);
      acc[1] = MFMA16(a, __builtin_bit_cast(bf16x8, b1), acc[1]);
      acc[2] = MFMA16(a, __builtin_bit_cast(bf16x8, b2), acc[2]);
    }

    if (s > 0) {
#pragma unroll
      for (int ct = 0; ct < 3; ++ct)
        *(f32x4*)&red[t & 1][s - 1][ct][lane * 4] = acc[ct];
    }
    __syncthreads();  // the ONLY per-step sync: exports ready AND (transitively
                      // via the 4 waves' tag-gated loads) all 64 producers of
                      // h_t published -> parity slot h_{t-1} fully consumed

    if (s == 0) {
      f32x4 a0 = acc[0], a1 = acc[1], a2 = acc[2];
#pragma unroll
      for (int j = 0; j < 3; ++j) {
        a0 += *(const f32x4*)&red[t & 1][j][0][lane * 4];
        a1 += *(const f32x4*)&red[t & 1][j][1][lane * 4];
        a2 += *(const f32x4*)&red[t & 1][j][2][lane * 4];
      }
#pragma unroll
      for (int i = 0; i < 4; ++i) {
        const float xr = b2f(gxr[i][0]);
        const float xz = b2f(gxr[i][1]);
        const float xn = b2f(gxr[i][2]);
        const float rr = sigm(xr + a0[i] + bhv[0]);
        const float zz = sigm(xz + a1[i] + bhv[1]);
        const float nn = tanh_fast(xn + rr * (a2[i] + bhv[2]));
        const float hnew = (1.0f - zz) * nn + zz * hprev[i];
        hprev[i] = hnew;
        htile[hq * 4 + i][c] = f2b(hnew);   // stage 16x16 tile for burst store
      }
      asm volatile("s_waitcnt lgkmcnt(0)" ::: "memory");
      __builtin_amdgcn_sched_barrier(0);
      u32x4 hv;
      if (lane < 32) {
        hv = *(const u32x4*)((const u16*)htile + lane * 8);
        st16_sc(hbuf + (((size_t)((t + 1) & 1) * 4 + r) * 64 + g) * 256 + lane * 8, hv);
      }
      asm volatile("s_waitcnt vmcnt(0)" ::: "memory");  // h tile at LLC
      if (lane == 0)
        st4_sc(tags + (((size_t)((t + 1) & 1) * 4 + r) * 64 + g) * 32, (u32)(t + 1));
      // off-critical-path: outs copy + next gx prefetch (hidden under poll)
      if (lane < 32) {
        const int row = row0 + (lane >> 1), c8 = (lane & 1) * 8;
        *(u32x4*)(outs + ((size_t)t * 64 + row) * 1024 + g * 16 + c8) = hv;
      }
      if (t < 255) {
        const u16* gp = gx + (size_t)(t + 1) * 64 * 3072 + gcol;
#pragma unroll
        for (int i = 0; i < 4; ++i) {
          const int b = row0 + hq * 4 + i;
          gxr[i][0] = gp[(size_t)b * 3072];
          gxr[i][1] = gp[(size_t)b * 3072 + 1024];
          gxr[i][2] = gp[(size_t)b * 3072 + 2048];
        }
      }
    }
  }
}

// ---------------- host ----------------
extern "C" void kernel_launch(void* const* d_in, const int* in_sizes, int n_in,
                              void* d_out, int out_size, void* d_ws, size_t ws_size,
                              hipStream_t stream) {
  (void)in_sizes; (void)n_in; (void)out_size; (void)ws_size;
  const int* y = (const int*)d_in[0];
  const float* hidden = (const float*)d_in[1];
  const float* emb = (const float*)d_in[2];
  const float* Wx = (const float*)d_in[3];
  const float* Wh = (const float*)d_in[4];
  const float* bx = (const float*)d_in[5];
  const float* bh = (const float*)d_in[6];
  const float* Wout = (const float*)d_in[7];
  const float* bout = (const float*)d_in[8];

  char* p = (char*)d_ws;
  u16* wx_t = (u16*)p; p += (size_t)3072 * 512 * 2;     // Wx^T  [3072][512]
  u16* wh_t = (u16*)p; p += (size_t)3072 * 1024 * 2;    // Wh^T  [3072][1024]
  u16* wo_t = (u16*)p; p += (size_t)512 * 1024 * 2;     // Wout^T[512][1024]
  u16* aemb = (u16*)p; p += (size_t)16384 * 512 * 2;    // gathered emb bf16
  u16* gx   = (u16*)p; p += (size_t)16384 * 3072 * 2;   // t-major gx
  u16* outs = (u16*)p; p += (size_t)16384 * 1024 * 2;   // h_1..h_256, t-major
  u16* hbuf = (u16*)p; p += (size_t)2 * 4 * 64 * 256 * 2; // blocked exchange
  u32* tags = (u32*)p;                                   // [2][4][64][32]

  hipMemsetAsync(tags, 0, 2 * 4 * 64 * 32 * sizeof(u32), stream);
  transpose_cvt<<<dim3(96, 16), dim3(32, 8), 0, stream>>>(Wx, wx_t, 512, 3072);
  transpose_cvt<<<dim3(96, 32), dim3(32, 8), 0, stream>>>(Wh, wh_t, 1024, 3072);
  transpose_cvt<<<dim3(16, 32), dim3(32, 8), 0, stream>>>(Wout, wo_t, 1024, 512);
  gather_cast<<<dim3(8192), dim3(256), 0, stream>>>(y, emb, aemb);
  cast_h0_blocked<<<dim3(256), dim3(256), 0, stream>>>(hidden, hbuf);

  // gx = emb @ Wx + bx   (M=16384, N=3072, K=512)
  gemm_bt<0><<<dim3(24, 128), dim3(256), 0, stream>>>(aemb, wx_t, bx, (void*)gx,
                                                      16384, 3072, 512);
  // GRU scan (persistent 256 WGs x 4 waves, blocked exchange + padded tags)
  scan_kernel<<<dim3(256), dim3(256), 0, stream>>>(wh_t, bh, hidden, gx,
                                                   hbuf, outs, tags);
  // logits = tanh(h_1..h_256 @ Wout + bout)  (M=16384, N=512, K=1024)
  gemm_bt<1><<<dim3(4, 128), dim3(256), 0, stream>>>(outs, wo_t, bout,
                                                     d_out, 16384, 512, 1024);
}